// Round 1
// baseline (338.328 us; speedup 1.0000x reference)
//
#include <hip/hip_runtime.h>
#include <math.h>

#define BLOCK 256
#define NUM_ITER 10
#define Z_MIN 0.1f
#define EPS_GN 1e-5
#define MIN_LM_DIAG 1e-6
#define MAX_LM_DIAG 1e32
#define MIN_REL_DECREASE 1e-3
#define INIT_RADIUS 30.0
#define MAX_RADIUS 1e16

// 4x4 linear solve, partial pivoting, f64. Runs on a single thread.
__device__ inline void solve4(double A[4][4], double b[4], double x[4]) {
    for (int k = 0; k < 4; ++k) {
        int m = k;
        double best = fabs(A[k][k]);
        for (int i = k + 1; i < 4; ++i) {
            double v = fabs(A[i][k]);
            if (v > best) { best = v; m = i; }
        }
        if (m != k) {
            for (int j = 0; j < 4; ++j) { double t = A[k][j]; A[k][j] = A[m][j]; A[m][j] = t; }
            double t = b[k]; b[k] = b[m]; b[m] = t;
        }
        double inv = 1.0 / A[k][k];
        for (int i = k + 1; i < 4; ++i) {
            double f = A[i][k] * inv;
            for (int j = k + 1; j < 4; ++j) A[i][j] -= f * A[k][j];
            b[i] -= f * b[k];
        }
    }
    for (int i = 3; i >= 0; --i) {
        double s = b[i];
        for (int j = i + 1; j < 4; ++j) s -= A[i][j] * x[j];
        x[i] = s / A[i][i];
    }
}

// One block per batch item. PPT points per thread held in registers.
template <int PPT>
__global__ __launch_bounds__(BLOCK) void lm_kernel(
    const float* __restrict__ x3d, const float* __restrict__ x2d,
    const float* __restrict__ w2d, const float* __restrict__ pose_init,
    const float* __restrict__ K, float* __restrict__ out, int B, int N)
{
    const int b    = blockIdx.x;
    const int tid  = threadIdx.x;
    const int lane = tid & 63;
    const int wave = tid >> 6;

    __shared__ float s_pose[4];
    __shared__ float s_sc[2];       // sin(yaw), cos(yaw)
    __shared__ float s_red[4][16];  // per-wave partials (15 used)

    // K is wave-uniform per block
    const float* Kb = K + (size_t)b * 9;
    const float K00 = Kb[0], K01 = Kb[1], K02 = Kb[2];
    const float K10 = Kb[3], K11 = Kb[4], K12 = Kb[5];
    const float K20 = Kb[6], K21 = Kb[7], K22 = Kb[8];

    // Load this thread's points into registers (inputs read exactly once)
    float pX[PPT], pY[PPT], pZ[PPT], pU[PPT], pV[PPT], pWu[PPT], pWv[PPT];
    const float* x3b = x3d + (size_t)b * N * 3;
    const float* x2b = x2d + (size_t)b * N * 2;
    const float* w2b = w2d + (size_t)b * N * 2;
#pragma unroll
    for (int i = 0; i < PPT; ++i) {
        int p = tid + i * BLOCK;
        if (p < N) {
            pX[i]  = x3b[3 * p];     pY[i] = x3b[3 * p + 1]; pZ[i] = x3b[3 * p + 2];
            pU[i]  = x2b[2 * p];     pV[i] = x2b[2 * p + 1];
            pWu[i] = w2b[2 * p];     pWv[i] = w2b[2 * p + 1];
        } else {
            pX[i] = pY[i] = pZ[i] = pU[i] = pV[i] = pWu[i] = pWv[i] = 0.f;
        }
    }

    // Thread-0 persistent LM state
    float  poseA[4] = {0.f, 0.f, 0.f, 0.f};
    float  pose_cand[4] = {0.f, 0.f, 0.f, 0.f};
    double JtJ[10], grad[4], cost = 0.0;
    double radius = INIT_RADIUS, dec = 2.0, mcc = 0.0;
#pragma unroll
    for (int k = 0; k < 10; ++k) JtJ[k] = 0.0;
#pragma unroll
    for (int k = 0; k < 4; ++k) grad[k] = 0.0;

    if (tid == 0) {
#pragma unroll
        for (int i = 0; i < 4; ++i) {
            poseA[i] = pose_init[(size_t)b * 4 + i];
            s_pose[i] = poseA[i];
        }
        s_sc[0] = sinf(poseA[3]);
        s_sc[1] = cosf(poseA[3]);
    }

    // it==0: evaluate at pose_init (scan init). it=1..NUM_ITER: evaluate candidates.
    for (int it = 0; it <= NUM_ITER; ++it) {
        __syncthreads();
        const float tx = s_pose[0], ty = s_pose[1], tz = s_pose[2];
        const float sn = s_sc[0],  cs = s_sc[1];

        // acc layout: 0..9 = JtJ upper tri (00,01,02,03,11,12,13,22,23,33),
        //             10..13 = grad, 14 = 2*cost
        float acc[15];
#pragma unroll
        for (int k = 0; k < 15; ++k) acc[k] = 0.f;

#pragma unroll
        for (int i = 0; i < PPT; ++i) {
            int p = tid + i * BLOCK;
            if (p >= N) break;
            const float X = pX[i], Y = pY[i], Z = pZ[i];
            const float px = fmaf(cs, X, fmaf(sn, Z, tx));
            const float py = Y + ty;
            const float pz = fmaf(-sn, X, fmaf(cs, Z, tz));
            const float nu = fmaf(K00, px, fmaf(K01, py, K02 * pz));
            const float nv = fmaf(K10, px, fmaf(K11, py, K12 * pz));
            const float w  = fmaf(K20, px, fmaf(K21, py, K22 * pz));
            const float zc  = fmaxf(w, Z_MIN);
            const float inv = 1.0f / zc;
            const float u = nu * inv, v = nv * inv;
            const float ru = (u - pU[i]) * pWu[i];
            const float rv = (v - pV[i]) * pWv[i];
            const float fl  = (w > Z_MIN) ? 1.f : 0.f;  // d(max(w,ZMIN))/dw
            const float ufl = u * fl, vfl = v * fl;
            const float gu = pWu[i] * inv, gv = pWv[i] * inv;
            // dp/dyaw = (a, 0, bb)
            const float a  = pz - tz;   // -s*X + c*Z
            const float bb = tx - px;   // -(c*X + s*Z)
            const float dnu3 = fmaf(K00, a, K02 * bb);
            const float dnv3 = fmaf(K10, a, K12 * bb);
            const float dw3  = fmaf(K20, a, K22 * bb);
            float Ju[4], Jv[4];
            Ju[0] = gu * fmaf(-ufl, K20, K00);  Jv[0] = gv * fmaf(-vfl, K20, K10);
            Ju[1] = gu * fmaf(-ufl, K21, K01);  Jv[1] = gv * fmaf(-vfl, K21, K11);
            Ju[2] = gu * fmaf(-ufl, K22, K02);  Jv[2] = gv * fmaf(-vfl, K22, K12);
            Ju[3] = gu * fmaf(-ufl, dw3, dnu3); Jv[3] = gv * fmaf(-vfl, dw3, dnv3);
            int idx = 0;
#pragma unroll
            for (int r = 0; r < 4; ++r)
#pragma unroll
                for (int c = r; c < 4; ++c) {
                    acc[idx] = fmaf(Ju[r], Ju[c], fmaf(Jv[r], Jv[c], acc[idx]));
                    ++idx;
                }
#pragma unroll
            for (int r = 0; r < 4; ++r)
                acc[10 + r] = fmaf(Ju[r], ru, fmaf(Jv[r], rv, acc[10 + r]));
            acc[14] = fmaf(ru, ru, fmaf(rv, rv, acc[14]));
        }

        // wave (64-lane) shuffle reduction of the 15 partials
#pragma unroll
        for (int k = 0; k < 15; ++k) {
            float v = acc[k];
#pragma unroll
            for (int off = 32; off > 0; off >>= 1) v += __shfl_down(v, off, 64);
            acc[k] = v;
        }
        if (lane == 0) {
#pragma unroll
            for (int k = 0; k < 15; ++k) s_red[wave][k] = acc[k];
        }
        __syncthreads();

        if (tid == 0) {
            double sum[15];
#pragma unroll
            for (int k = 0; k < 15; ++k)
                sum[k] = (double)s_red[0][k] + (double)s_red[1][k] +
                         (double)s_red[2][k] + (double)s_red[3][k];
            const double costN = 0.5 * sum[14];

            bool accept;
            if (it == 0) {
                accept = true;
            } else {
                const double rel = (cost - costN) / mcc;
                const bool success = (rel >= MIN_REL_DECREASE) && (mcc > 0.0);
                if (success) {
                    const double q = 2.0 * rel - 1.0;
                    const double denom = fmax(1.0 - q * q * q, 1.0 / 3.0);
                    radius = fmin(radius / denom, MAX_RADIUS);
                    dec = 2.0;
                } else {
                    radius = radius / dec;
                    dec = dec * 2.0;
                }
                accept = success;
            }
            if (accept) {
#pragma unroll
                for (int k = 0; k < 10; ++k) JtJ[k] = sum[k];
#pragma unroll
                for (int k = 0; k < 4; ++k) grad[k] = sum[10 + k];
                cost = costN;
                if (it > 0) {
#pragma unroll
                    for (int k = 0; k < 4; ++k) poseA[k] = pose_cand[k];
                }
            }

            if (it < NUM_ITER) {
                // Build LM-damped system from accepted JtJ/grad, solve for step
                double A[4][4] = {
                    {JtJ[0], JtJ[1], JtJ[2], JtJ[3]},
                    {JtJ[1], JtJ[4], JtJ[5], JtJ[6]},
                    {JtJ[2], JtJ[5], JtJ[7], JtJ[8]},
                    {JtJ[3], JtJ[6], JtJ[8], JtJ[9]}};
                double rhs[4], stepv[4];
#pragma unroll
                for (int r = 0; r < 4; ++r) {
                    double d = A[r][r];
                    d = fmin(fmax(d, MIN_LM_DIAG), MAX_LM_DIAG);
                    A[r][r] += d / radius;
                    rhs[r] = -grad[r];
                }
                solve4(A, rhs, stepv);
                float stf[4];
#pragma unroll
                for (int r = 0; r < 4; ++r) {
                    stf[r] = (float)stepv[r];
                    pose_cand[r] = poseA[r] + stf[r];  // f32 add, matches ref
                }
                // model cost change with undamped JtJ, f32-rounded step
                const double s0 = stf[0], s1 = stf[1], s2 = stf[2], s3 = stf[3];
                const double Js0 = JtJ[0]*s0 + JtJ[1]*s1 + JtJ[2]*s2 + JtJ[3]*s3;
                const double Js1 = JtJ[1]*s0 + JtJ[4]*s1 + JtJ[5]*s2 + JtJ[6]*s3;
                const double Js2 = JtJ[2]*s0 + JtJ[5]*s1 + JtJ[7]*s2 + JtJ[8]*s3;
                const double Js3 = JtJ[3]*s0 + JtJ[6]*s1 + JtJ[8]*s2 + JtJ[9]*s3;
                mcc = -((s0*grad[0] + s1*grad[1] + s2*grad[2] + s3*grad[3]) +
                        0.5 * (s0*Js0 + s1*Js1 + s2*Js2 + s3*Js3));
                s_pose[0] = pose_cand[0];
                s_pose[1] = pose_cand[1];
                s_pose[2] = pose_cand[2];
                s_pose[3] = pose_cand[3];
                s_sc[0] = sinf(pose_cand[3]);
                s_sc[1] = cosf(pose_cand[3]);
            } else {
                // Epilogue: pose_opt, cost, pose_opt + GN step (reuses accepted JtJ/grad)
                float* out_pose = out;
                float* out_cost = out + (size_t)B * 4;
                float* out_plus = out + (size_t)B * 5;
#pragma unroll
                for (int r = 0; r < 4; ++r) out_pose[(size_t)b * 4 + r] = poseA[r];
                out_cost[b] = (float)cost;
                double A[4][4] = {
                    {JtJ[0] + EPS_GN, JtJ[1], JtJ[2], JtJ[3]},
                    {JtJ[1], JtJ[4] + EPS_GN, JtJ[5], JtJ[6]},
                    {JtJ[2], JtJ[5], JtJ[7] + EPS_GN, JtJ[8]},
                    {JtJ[3], JtJ[6], JtJ[8], JtJ[9] + EPS_GN}};
                double rhs[4], stepv[4];
#pragma unroll
                for (int r = 0; r < 4; ++r) rhs[r] = -grad[r];
                solve4(A, rhs, stepv);
#pragma unroll
                for (int r = 0; r < 4; ++r)
                    out_plus[(size_t)b * 4 + r] = poseA[r] + (float)stepv[r];
            }
        }
    }
}

extern "C" void kernel_launch(void* const* d_in, const int* in_sizes, int n_in,
                              void* d_out, int out_size, void* d_ws, size_t ws_size,
                              hipStream_t stream) {
    const float* x3d       = (const float*)d_in[0];
    const float* x2d       = (const float*)d_in[1];
    const float* w2d       = (const float*)d_in[2];
    const float* pose_init = (const float*)d_in[3];
    const float* cam       = (const float*)d_in[4];
    float* out = (float*)d_out;

    const int B = in_sizes[3] / 4;
    const int N = in_sizes[0] / (3 * B);

    if (N <= BLOCK) {
        lm_kernel<1><<<B, BLOCK, 0, stream>>>(x3d, x2d, w2d, pose_init, cam, out, B, N);
    } else if (N <= 2 * BLOCK) {
        lm_kernel<2><<<B, BLOCK, 0, stream>>>(x3d, x2d, w2d, pose_init, cam, out, B, N);
    } else if (N <= 4 * BLOCK) {
        lm_kernel<4><<<B, BLOCK, 0, stream>>>(x3d, x2d, w2d, pose_init, cam, out, B, N);
    } else {
        lm_kernel<8><<<B, BLOCK, 0, stream>>>(x3d, x2d, w2d, pose_init, cam, out, B, N);
    }
}